// Round 6
// baseline (257.565 us; speedup 1.0000x reference)
//
#include <hip/hip_runtime.h>

using f32x4  = __attribute__((ext_vector_type(4))) float;
using f32x16 = __attribute__((ext_vector_type(16))) float;
using bf16x8 = __attribute__((ext_vector_type(8))) short;
using u32x4  = __attribute__((ext_vector_type(4))) unsigned int;
using u32x2  = __attribute__((ext_vector_type(2))) unsigned int;
typedef unsigned short u16;

__device__ __forceinline__ u16 f2bf(float f) {
  unsigned u = __float_as_uint(f);
  unsigned r = (u + 0x7FFFu + ((u >> 16) & 1u)) >> 16;
  return (u16)r;
}

// exp2 path: featB is pre-scaled by log2(e) in k1, so exp(s) == exp2(s_scaled).
#if __has_builtin(__builtin_amdgcn_exp2f)
#define FAST_EXP2(x) __builtin_amdgcn_exp2f(x)
#else
#define FAST_EXP2(x) __expf(0.6931471805599453f * (x))
#endif

#define LOG2E 1.4426950408889634f

// a' = {a.lo32lanes, b.lo32lanes}; b' = {a.hi32lanes, b.hi32lanes}
__device__ __forceinline__ void permswap32(unsigned& a, unsigned& b) {
  asm volatile("v_permlane32_swap_b32 %0, %1" : "+v"(a), "+v"(b));
}

// ---------------- Kernel 1: 1x1 convs (+ z=3: conv3x3 weight cvt -> lane-linear MFMA tiles)
__global__ void __launch_bounds__(256) k1_conv1x1(
    const float* __restrict__ x, const float* __restrict__ wB, const float* __restrict__ bB,
    const float* __restrict__ wC, const float* __restrict__ bC,
    const float* __restrict__ wD, const float* __restrict__ bD,
    u16* __restrict__ featBb, u16* __restrict__ featCb, u16* __restrict__ featD,
    const float* __restrict__ cw, u16* __restrict__ wb) {
  const int t = threadIdx.x;
  const int b = blockIdx.y;
  const int z = blockIdx.z;
  if (z == 3) {
    int gid = (b * 16 + blockIdx.x) * 256 + t;
#pragma unroll
    for (int k = 0; k < 3; ++k) {
      int F = gid + k * 32768;
      if (F < 73728) {
        int j = F & 7, lane = (F >> 3) & 63, T = F >> 9;
        int tap = T >> 4, g = (T >> 1) & 7, kc = T & 1;
        int l16 = lane & 15, quad = lane >> 4;
        int oc = g * 16 + l16, ic = kc * 32 + quad * 8 + j;
        wb[F] = f2bf(cw[(oc * 64 + ic) * 9 + tap]);
      }
    }
    return;
  }
  __shared__ float W[2048];
  __shared__ float Bias[32];
  const int n = blockIdx.x * 256 + t;
  if (z == 0) {
    for (int i = t; i < 512; i += 256) W[i] = wB[i];
    for (int i = t; i < 512; i += 256) W[512 + i] = wC[i];
    if (t < 8) Bias[t] = bB[t];
    if (t >= 8 && t < 16) Bias[t] = bC[t - 8];
  } else {
    const float* wsrc = wD + (z - 1) * 2048;
    for (int i = t; i < 2048; i += 256) W[i] = wsrc[i];
    if (t < 32) Bias[t] = bD[(z - 1) * 32 + t];
  }
  __syncthreads();
  float xv[64];
#pragma unroll
  for (int c = 0; c < 64; ++c) xv[c] = x[((b * 64 + c) << 12) + n];
  if (z == 0) {
    float o[16];
#pragma unroll
    for (int k = 0; k < 16; ++k) {
      f32x4 s = {0.f, 0.f, 0.f, 0.f};
#pragma unroll
      for (int cq = 0; cq < 16; ++cq) {
        f32x4 wv = *(const f32x4*)&W[k * 64 + cq * 4];
        f32x4 xq = {xv[cq * 4], xv[cq * 4 + 1], xv[cq * 4 + 2], xv[cq * 4 + 3]};
        s += wv * xq;
      }
      o[k] = Bias[k] + s[0] + s[1] + s[2] + s[3];
    }
    int base = ((b << 12) + n) * 8;
    u32x4 pb, pc;
#pragma unroll
    for (int i = 0; i < 4; ++i) {
      // featB pre-scaled by log2(e) so k2 can use raw v_exp_f32 (exp2)
      pb[i] = (unsigned)f2bf(o[2 * i] * LOG2E) | ((unsigned)f2bf(o[2 * i + 1] * LOG2E) << 16);
      pc[i] = (unsigned)f2bf(o[8 + 2 * i]) | ((unsigned)f2bf(o[8 + 2 * i + 1]) << 16);
    }
    *(u32x4*)&featBb[base] = pb;
    *(u32x4*)&featCb[base] = pc;
  } else {
#pragma unroll 4
    for (int k = 0; k < 32; ++k) {
      f32x4 s = {0.f, 0.f, 0.f, 0.f};
#pragma unroll
      for (int cq = 0; cq < 16; ++cq) {
        f32x4 wv = *(const f32x4*)&W[k * 64 + cq * 4];
        f32x4 xq = {xv[cq * 4], xv[cq * 4 + 1], xv[cq * 4 + 2], xv[cq * 4 + 3]};
        s += wv * xq;
      }
      float val = Bias[k] + s[0] + s[1] + s[2] + s[3];
      featD[((b * 64 + (z - 1) * 32 + k) << 12) + n] = f2bf(val);
    }
  }
}

// ---------------- Kernel 2: PAM partial attention, 32x32x16 MFMA, register-resident P.
// R17: occupancy model — waves/SIMD steps at unified-reg budgets {64:8, 128:4, 256:2}.
// R14-R16 sat at ~148 regs (100 VGPR + 48 AGPR) = 2 waves/SIMD bucket -> 17% occupancy,
// ~4.5x idle per SIMD. Diet to <=128: drop sn pipeline (R16-null, -16), drop accd/onesA
// den-MFMA and revert to VALU dsum (-24; +18% VALU absorbed by 2x TLP), enforce with
// __launch_bounds__(256,4). Keep: Df dbuf issue-early/write-late, afv prefetch,
// setprio around PV, one barrier/iter.
__global__ void __launch_bounds__(256, 4) k2_pam_part(
    const u16* __restrict__ fBb, const u16* __restrict__ fCb, const u16* __restrict__ fD,
    u16* __restrict__ numPart, float* __restrict__ denPart) {
  __shared__ u16 Df[2][64 * 132];  // 33.8 KB
  const int t = threadIdx.x, b = blockIdx.y, z = blockIdx.z;
  const int w = t >> 6, lane = t & 63, l32 = lane & 31, hi = lane >> 5;
  const int nb = blockIdx.x * 128 + w * 32;  // wave's 32-n tile
  const int mz = z << 10;

  // staging coords (loop-invariant): thread covers 4 chunks of Df[64][128]
  int srow[4], smo[4];
#pragma unroll
  for (int hh = 0; hh < 4; ++hh) {
    int idx = hh * 256 + t;
    srow[hh] = idx >> 4;
    smo[hh] = (idx & 15) << 3;
  }

  // Q fragment: B[k][n], lane (n=l32, hi): k = hi*8+j. Real K = 8 -> hi lanes zero.
  bf16x8 bq = (bf16x8)(short)0;
  if (hi == 0) bq = *(const bf16x8*)&fBb[(((b << 12) + nb + l32) << 3)];

  f32x16 acc0 = (f32x16)(0.0f), acc1 = (f32x16)(0.0f);
  float denp = 0.f;

  u32x4 sreg[4];
#define K2_ISSUE(CH) {                                                        \
    int m0_ = mz + ((CH) << 7);                                               \
    _Pragma("unroll")                                                         \
    for (int hh = 0; hh < 4; ++hh)                                            \
      sreg[hh] = *(const u32x4*)&fD[((b * 64 + srow[hh]) << 12) + m0_ + smo[hh]]; }
#define K2_WRITE(BUF) {                                                       \
    _Pragma("unroll")                                                         \
    for (int hh = 0; hh < 4; ++hh)                                            \
      *(u32x4*)&Df[BUF][srow[hh] * 132 + smo[hh]] = sreg[hh]; }

  K2_ISSUE(0);
  K2_WRITE(0);
  __syncthreads();

#pragma unroll 2
  for (int ch = 0; ch < 8; ++ch) {
    const int cur = ch & 1;
    const int m0 = mz + (ch << 7);
    if (ch < 7) K2_ISSUE(ch + 1);  // next tile: global -> regs, lands under compute

    // prefetch af (fCb) for all 4 mt2: off the S critical path
    bf16x8 afv[4];
#pragma unroll
    for (int mt2 = 0; mt2 < 4; ++mt2) {
      bf16x8 a = (bf16x8)(short)0;
      if (hi == 0) a = *(const bf16x8*)&fCb[(((b << 12) + m0 + mt2 * 32 + l32) << 3)];
      afv[mt2] = a;
    }

#pragma unroll
    for (int mt2 = 0; mt2 < 4; ++mt2) {
      // S = K.Q^T (32x32): lane (n=l32,hi), reg r: m = (r&3)+8*(r>>2)+4*hi
      f32x16 sc = __builtin_amdgcn_mfma_f32_32x32x16_bf16(afv[mt2], bq, (f32x16)(0.0f), 0, 0, 0);
      // exp, den-sum, pack bf16 pairs
      unsigned u0[8];
      float dsum = 0.f;
#pragma unroll
      for (int i = 0; i < 8; ++i) {
        float e0 = FAST_EXP2(sc[2 * i]);
        float e1 = FAST_EXP2(sc[2 * i + 1]);
        dsum += e0 + e1;
        u0[i] = __builtin_amdgcn_perm(__float_as_uint(e1), __float_as_uint(e0), 0x07060302u);
      }
      denp += dsum;
      // Rearrange to PV B-frag: for kc, reg p: pair(m = kc*16 + hi*8 + 2p)
      permswap32(u0[0], u0[2]); permswap32(u0[1], u0[3]);
      permswap32(u0[4], u0[6]); permswap32(u0[5], u0[7]);

      // PV: out[c,n] += D[c,m]*P[n,m]
      __builtin_amdgcn_s_setprio(1);
#pragma unroll
      for (int kc = 0; kc < 2; ++kc) {
        u32x4 q0 = {u0[4 * kc], u0[4 * kc + 1], u0[4 * kc + 2], u0[4 * kc + 3]};
        bf16x8 bv0 = *(bf16x8*)&q0;
        bf16x8 av0 = *(const bf16x8*)&Df[cur][(l32) * 132 + mt2 * 32 + kc * 16 + hi * 8];
        bf16x8 av1 = *(const bf16x8*)&Df[cur][(32 + l32) * 132 + mt2 * 32 + kc * 16 + hi * 8];
        acc0 = __builtin_amdgcn_mfma_f32_32x32x16_bf16(av0, bv0, acc0, 0, 0, 0);
        acc1 = __builtin_amdgcn_mfma_f32_32x32x16_bf16(av1, bv0, acc1, 0, 0, 0);
      }
      __builtin_amdgcn_s_setprio(0);
    }

    if (ch < 7) K2_WRITE(cur ^ 1);  // safe: buf cur^1 last read before prev barrier
    __syncthreads();
  }
#undef K2_ISSUE
#undef K2_WRITE

  const int zb = z * 8 + b;
#pragma unroll
  for (int r = 0; r < 16; ++r) {
    int c = (r & 3) + ((r >> 2) << 3) + (hi << 2);
    numPart[((zb * 64 + c) << 12) + nb + l32] = (u16)(__float_as_uint(acc0[r]) >> 16);
    numPart[((zb * 64 + c + 32) << 12) + nb + l32] = (u16)(__float_as_uint(acc1[r]) >> 16);
  }
  {
    float d = denp + __shfl_xor(denp, 32);
    if (hi == 0) denPart[(zb << 12) + nb + l32] = d;
  }
}

// ---------------- Kernel 3: reduce PAM partials -> x1 (global + LDS), then CAM gram partials
__global__ void __launch_bounds__(256) k3_gram(
    const u16* __restrict__ numPart, const float* __restrict__ denPart,
    const float* __restrict__ x, const float* __restrict__ alpha,
    float* __restrict__ x1, float* __restrict__ attPart) {
  __shared__ float X[64 * 132];
  __shared__ float Dinv[128];
  const int t = threadIdx.x, b = blockIdx.y, cx = blockIdx.x;
  const int n0 = cx * 128;
  if (t < 128) {
    float den = 0.f;
#pragma unroll
    for (int z = 0; z < 4; ++z) den += denPart[(((z * 8 + b) << 12)) + n0 + t];
    Dinv[t] = alpha[0] / den;
  }
  __syncthreads();
  for (int idx = t; idx < 4096; idx += 256) {
    int row = idx >> 6, cp = (idx & 63) * 2;
    int gi = ((b * 64 + row) << 12) + n0 + cp;
    float num0 = 0.f, num1 = 0.f;
#pragma unroll
    for (int z = 0; z < 4; ++z) {
      unsigned v = *(const unsigned*)&numPart[(((z * 8 + b) * 64 + row) << 12) + n0 + cp];
      num0 += __uint_as_float(v << 16);
      num1 += __uint_as_float(v & 0xFFFF0000u);
    }
    float v0 = num0 * Dinv[cp] + x[gi];
    float v1 = num1 * Dinv[cp + 1] + x[gi + 1];
    X[row * 132 + cp] = v0;
    X[row * 132 + cp + 1] = v1;
    x1[gi] = v0;
    x1[gi + 1] = v1;
  }
  __syncthreads();
  const int cg = t >> 4, dg = t & 15;
  f32x4 acc[4][4];
#pragma unroll
  for (int i = 0; i < 4; ++i)
#pragma unroll
    for (int k = 0; k < 4; ++k) acc[i][k] = (f32x4){0.f, 0.f, 0.f, 0.f};
  for (int nq0 = 0; nq0 < 32; ++nq0) {
    int nq = (nq0 + dg) & 31;
    f32x4 a[4], bb[4];
#pragma unroll
    for (int i = 0; i < 4; ++i) a[i] = *(const f32x4*)&X[(cg * 4 + i) * 132 + nq * 4];
#pragma unroll
    for (int k = 0; k < 4; ++k) bb[k] = *(const f32x4*)&X[(dg * 4 + k) * 132 + nq * 4];
#pragma unroll
    for (int i = 0; i < 4; ++i)
#pragma unroll
      for (int k = 0; k < 4; ++k) acc[i][k] += a[i] * bb[k];
  }
#pragma unroll
  for (int i = 0; i < 4; ++i)
#pragma unroll
    for (int k = 0; k < 4; ++k) {
      f32x4 s = acc[i][k];
      attPart[((b * 32 + cx) * 64 + cg * 4 + i) * 64 + dg * 4 + k] = s[0] + s[1] + s[2] + s[3];
    }
}

// ---------------- Kernel 4: CAM softmax (min-form), one wave per c-row. grid (16, 8)
__global__ void __launch_bounds__(256) k4_softmax(const float* __restrict__ attPart, float* __restrict__ attP) {
  const int b = blockIdx.y, t = threadIdx.x;
  const int c = (blockIdx.x << 2) + (t >> 6), d = t & 63;
  float v = 0.f;
  for (int p = 0; p < 32; ++p) v += attPart[((b * 32 + p) * 64 + c) * 64 + d];
  float mn = v;
#pragma unroll
  for (int off = 1; off < 64; off <<= 1) mn = fminf(mn, __shfl_xor(mn, off));
  float e = __expf(mn - v);
  float sum = e;
#pragma unroll
  for (int off = 1; off < 64; off <<= 1) sum += __shfl_xor(sum, off);
  attP[(b * 64 + c) * 64 + d] = e / sum;
}

// ---------------- Kernel 5: x2 = beta*(attP @ x1) + x1, bf16 NHWC.
// grid (64,8): thread = (n, c-quad), 16 scalar accs, x1 streamed from L2.
__global__ void __launch_bounds__(256) k5_apply(
    const float* __restrict__ attP, const float* __restrict__ x1,
    const float* __restrict__ beta, u16* __restrict__ x2b) {
  __shared__ float A[64 * 68];
  const int t = threadIdx.x, b = blockIdx.y;
  for (int idx = t; idx < 4096; idx += 256) A[(idx >> 6) * 68 + (idx & 63)] = attP[(b << 12) + idx];
  __syncthreads();
  const int n = blockIdx.x * 64 + (t & 63);
  const int cq = t >> 6;
  const float bv = beta[0];
  float acc[16];
#pragma unroll
  for (int i = 0; i < 16; ++i) acc[i] = 0.f;
  const float* xcol = x1 + ((size_t)b << 18) + n;
#pragma unroll 4
  for (int dq = 0; dq < 16; ++dq) {
    float x0 = xcol[(size_t)(dq * 4 + 0) << 12];
    float x1v = xcol[(size_t)(dq * 4 + 1) << 12];
    float x2 = xcol[(size_t)(dq * 4 + 2) << 12];
    float x3 = xcol[(size_t)(dq * 4 + 3) << 12];
#pragma unroll
    for (int i = 0; i < 16; ++i) {
      const float* av = &A[(cq * 16 + i) * 68 + dq * 4];
      acc[i] += av[0] * x0 + av[1] * x1v + av[2] * x2 + av[3] * x3;
    }
  }
  u16* orow = x2b + ((((size_t)(b << 12) + n) << 6) + cq * 16);
  unsigned pk[8];
#pragma unroll
  for (int i = 0; i < 16; i += 2) {
    float v0 = bv * acc[i] + xcol[(size_t)(cq * 16 + i) << 12];
    float v1 = bv * acc[i + 1] + xcol[(size_t)(cq * 16 + i + 1) << 12];
    pk[i >> 1] = (unsigned)f2bf(v0) | ((unsigned)f2bf(v1) << 16);
  }
  *(u32x4*)&orow[0] = *(u32x4*)&pk[0];
  *(u32x4*)&orow[8] = *(u32x4*)&pk[4];
}

// ---------------- Kernel 6: conv3x3 bf16 MFMA, lane-linear weight tiles.
// Fused BN partial stats: per-(b,h)-block partial sum/sumsq -> private slot
// pstat2[(oc*2+st)*512 + b*64+h]; k8 reduces the 512 partials per channel.
__global__ void __launch_bounds__(256) k6_mfma(const u16* __restrict__ x2b, const u16* __restrict__ wb,
                                               float* __restrict__ y, float* __restrict__ pstat2) {
  __shared__ u16 Xl[3 * 66 * 72];
  __shared__ float pp[4][64][2];
  const int t = threadIdx.x, b = blockIdx.y, h = blockIdx.x;
  for (int idx = t; idx < 3 * 66 * 8; idx += 256) {
    int r = idx / 528;
    int rem = idx - r * 528;
    int c = rem >> 3, icq = rem & 7;
    int gy = h - 1 + r, gx = c - 1;
    u32x4 v = {0u, 0u, 0u, 0u};
    if (gy >= 0 && gy < 64 && gx >= 0 && gx < 64)
      v = *(const u32x4*)&x2b[(((size_t)(b << 6 | gy) << 6) + gx) * 64 + icq * 8];
    *(u32x4*)&Xl[(r * 66 + c) * 72 + icq * 8] = v;
  }
  __syncthreads();
  const int w = t >> 6, lane = t & 63, quad = lane >> 4, l16 = lane & 15;
  const int mBase = (w & 1) * 64;
  const int og = (w & 1) * 4;
  const int nBase = (w >> 1) * 32;
  f32x4 acc[4][2];
#pragma unroll
  for (int ot = 0; ot < 4; ++ot)
#pragma unroll
    for (int nt = 0; nt < 2; ++nt) acc[ot][nt] = (f32x4){0.f, 0.f, 0.f, 0.f};
#pragma unroll 3
  for (int tap = 0; tap < 9; ++tap) {
    const int dy = tap / 3, dx = tap - dy * 3;
    bf16x8 af[4][2];
#pragma unroll
    for (int ot = 0; ot < 4; ++ot)
#pragma unroll
      for (int kc = 0; kc < 2; ++kc)
        af[ot][kc] = *(const bf16x8*)&wb[((((tap * 8 + og + ot) * 2 + kc) << 6) + lane) << 3];
#pragma unroll
    for (int nt = 0; nt < 2; ++nt) {
      const int prow = dy * 66 + nBase + nt * 16 + l16 + dx;
#pragma unroll
      for (int kc = 0; kc < 2; ++kc) {
        bf16x8 bv = *(const bf16x8*)&Xl[prow * 72 + kc * 32 + quad * 8];
#pragma unroll
        for (int ot = 0; ot < 4; ++ot)
          acc[ot][nt] = __builtin_amdgcn_mfma_f32_16x16x32_bf16(af[ot][kc], bv, acc[ot][nt], 0, 0, 0);
      }
    }
  }
#pragma unroll
  for (int ot = 0; ot < 4; ++ot)
#pragma unroll
    for (int nt = 0; nt < 2; ++nt)
#pragma unroll
      for (int r = 0; r < 4; ++r) {
        int oc = mBase + ot * 16 + quad * 4 + r;
        int pix = nBase + nt * 16 + l16;
        y[((b * 128 + oc) << 12) + (h << 6) + pix] = acc[ot][nt][r];
      }
  // ---- fused BN partial stats
  float bs[4][4], bss[4][4];
#pragma unroll
  for (int ot = 0; ot < 4; ++ot)
#pragma unroll
    for (int r = 0; r < 4; ++r) {
      float v0 = acc[ot][0][r], v1 = acc[ot][1][r];
      bs[ot][r] = v0 + v1;
      bss[ot][r] = v0 * v0 + v1 * v1;
    }
#pragma unroll
  for (int off = 1; off < 16; off <<= 1) {
#pragma unroll
    for (int ot = 0; ot < 4; ++ot)
#pragma unroll
      for (int r = 0; r < 4; ++r) {
        bs[ot][r] += __shfl_xor(bs[ot][r], off);
        bss[ot][r] += __shfl_xor(bss[ot][r], off);
      }
  }
  if (l16 == 0) {
#pragma unroll
    for (int ot = 0; ot < 4; ++ot)
#pragma unroll
      for (int r = 0; r < 4; ++r) {
        int ocl = ot * 16 + quad * 4 + r;
        pp[w][ocl][0] = bs[ot][r];
        pp[w][ocl][1] = bss[ot][r];
      }
  }
  __syncthreads();
  {
    int oc = t >> 1, st = t & 1;
    float v = (oc < 64) ? (pp[0][oc][st] + pp[2][oc][st])
                        : (pp[1][oc - 64][st] + pp[3][oc - 64][st]);
    pstat2[(oc * 2 + st) * 512 + (b << 6) + h] = v;
  }
}

// ---------------- Kernel 8: BN finalize (from k6's 512 per-block partials) + ReLU + maxpool
__global__ void __launch_bounds__(256) k8_pool(const float* __restrict__ y, const float* __restrict__ pstat2,
                                               const float* __restrict__ gamma, const float* __restrict__ bbeta,
                                               float* __restrict__ out) {
  const int bc = blockIdx.x;
  const int ch = bc & 127;
  float s = 0.f, ss = 0.f;
  for (int i = threadIdx.x; i < 512; i += 256) {
    s += pstat2[ch * 1024 + i];
    ss += pstat2[ch * 1024 + 512 + i];
  }
#pragma unroll
  for (int off = 1; off < 64; off <<= 1) { s += __shfl_xor(s, off); ss += __shfl_xor(ss, off); }
  __shared__ float rs[4], rss[4];
  if ((threadIdx.x & 63) == 0) { rs[threadIdx.x >> 6] = s; rss[threadIdx.x >> 6] = ss; }
  __syncthreads();
  const float S = rs[0] + rs[1] + rs[2] + rs[3];
  const float SS = rss[0] + rss[1] + rss[2] + rss[3];
  const float mean = S * (1.f / 32768.f);
  const float var = SS * (1.f / 32768.f) - mean * mean;
  const float sc = gamma[ch] * rsqrtf(var + 1e-5f);
  const float sh = bbeta[ch] - mean * sc;
  const float* p = y + (bc << 12);
  float* op = out + bc * (33 * 32);
  for (int i = threadIdx.x; i < 33 * 32; i += 256) {
    int oh = i >> 5, ow = i & 31;
    int r0 = 2 * oh - 1, r1 = 2 * oh;
    float m = 0.f;
    if (r0 >= 0) {
      m = fmaxf(m, p[r0 * 64 + 2 * ow] * sc + sh);
      m = fmaxf(m, p[r0 * 64 + 2 * ow + 1] * sc + sh);
    }
    if (r1 <= 63) {
      m = fmaxf(m, p[r1 * 64 + 2 * ow] * sc + sh);
      m = fmaxf(m, p[r1 * 64 + 2 * ow + 1] * sc + sh);
    }
    op[i] = m;
  }
}

extern "C" void kernel_launch(void* const* d_in, const int* in_sizes, int n_in,
                              void* d_out, int out_size, void* d_ws, size_t ws_size,
                              hipStream_t stream) {
  const float* x      = (const float*)d_in[0];
  const float* wB     = (const float*)d_in[1];
  const float* bB     = (const float*)d_in[2];
  const float* wC     = (const float*)d_in[3];
  const float* bC     = (const float*)d_in[4];
  const float* wD     = (const float*)d_in[5];
  const float* bD     = (const float*)d_in[6];
  const float* alpha  = (const float*)d_in[7];
  const float* beta   = (const float*)d_in[8];
  const float* cw     = (const float*)d_in[9];
  const float* gamma  = (const float*)d_in[11];
  const float* bnbeta = (const float*)d_in[12];

  // Workspace overlays (35.3 MB):
  //  [0,4M):      featBb/featCb/fDb [k1..k2p]  then x2b [k5..k6]
  //  [5M,13M):    x1 [k3..k5]
  //  [13M,29.8M): numPart [k2p..k3]  then y [k6..k8]
  //  [29.0M+..]:  denPart, attPart (reused as pstat2 after k4), attP, wb
  char* ws = (char*)d_ws;
  u16*   featBb  = (u16*)  (ws + 0);          // 512 KB
  u16*   featCb  = (u16*)  (ws + 524288);     // 512 KB
  u16*   fDb     = (u16*)  (ws + 1048576);    // 4 MB
  u16*   x2b     = (u16*)  (ws + 0);          // 4 MB (bf16 NHWC) — over feat*
  float* x1      = (float*)(ws + 5242880);    // 8 MB
  u16*   numPart = (u16*)  (ws + 13631488);   // 16 MB
  float* y       = (float*)(ws + 13631488);   // 16 MB — over numPart
  float* denPart = (float*)(ws + 30408704);   // 512 KB
  float* attPart = (float*)(ws + 30932992);   // 4 MB
  float* pstat2  = (float*)(ws + 30932992);   // 512 KB — over attPart (dead after k4)
  float* attP    = (float*)(ws + 35127296);   // 128 KB
  u16*   wb      = (u16*)  (ws + 35258368);   // 144 KB
  float* outp    = (float*)d_out;

  k1_conv1x1<<<dim3(16, 8, 4), 256, 0, stream>>>(x, wB, bB, wC, bC, wD, bD, featBb, featCb, fDb, cw, wb);
  k2_pam_part<<<dim3(32, 8, 4), 256, 0, stream>>>(featBb, featCb, fDb, numPart, denPart);
  k3_gram<<<dim3(32, 8), 256, 0, stream>>>(numPart, denPart, x, alpha, x1, attPart);
  k4_softmax<<<dim3(16, 8), 256, 0, stream>>>(attPart, attP);
  k5_apply<<<dim3(64, 8), 256, 0, stream>>>(attP, x1, beta, x2b);
  k6_mfma<<<dim3(64, 8), 256, 0, stream>>>(x2b, wb, y, pstat2);
  k8_pool<<<dim3(1024), 256, 0, stream>>>(y, pstat2, gamma, bnbeta, outp);
}

// Round 7
// 186.896 us; speedup vs baseline: 1.3781x; 1.3781x over previous
//
#include <hip/hip_runtime.h>

using f32x4  = __attribute__((ext_vector_type(4))) float;
using f32x16 = __attribute__((ext_vector_type(16))) float;
using bf16x8 = __attribute__((ext_vector_type(8))) short;
using u32x4  = __attribute__((ext_vector_type(4))) unsigned int;
using u32x2  = __attribute__((ext_vector_type(2))) unsigned int;
typedef unsigned short u16;

__device__ __forceinline__ u16 f2bf(float f) {
  unsigned u = __float_as_uint(f);
  unsigned r = (u + 0x7FFFu + ((u >> 16) & 1u)) >> 16;
  return (u16)r;
}

// exp2 path: featB is pre-scaled by log2(e) in k1, so exp(s) == exp2(s_scaled).
#if __has_builtin(__builtin_amdgcn_exp2f)
#define FAST_EXP2(x) __builtin_amdgcn_exp2f(x)
#else
#define FAST_EXP2(x) __expf(0.6931471805599453f * (x))
#endif

#define LOG2E 1.4426950408889634f

// a' = {a.lo32lanes, b.lo32lanes}; b' = {a.hi32lanes, b.hi32lanes}
__device__ __forceinline__ void permswap32(unsigned& a, unsigned& b) {
  asm volatile("v_permlane32_swap_b32 %0, %1" : "+v"(a), "+v"(b));
}

// ---------------- Kernel 1: 1x1 convs (+ z=3: conv3x3 weight cvt -> lane-linear MFMA tiles)
__global__ void __launch_bounds__(256) k1_conv1x1(
    const float* __restrict__ x, const float* __restrict__ wB, const float* __restrict__ bB,
    const float* __restrict__ wC, const float* __restrict__ bC,
    const float* __restrict__ wD, const float* __restrict__ bD,
    u16* __restrict__ featBb, u16* __restrict__ featCb, u16* __restrict__ featD,
    const float* __restrict__ cw, u16* __restrict__ wb) {
  const int t = threadIdx.x;
  const int b = blockIdx.y;
  const int z = blockIdx.z;
  if (z == 3) {
    int gid = (b * 16 + blockIdx.x) * 256 + t;
#pragma unroll
    for (int k = 0; k < 3; ++k) {
      int F = gid + k * 32768;
      if (F < 73728) {
        int j = F & 7, lane = (F >> 3) & 63, T = F >> 9;
        int tap = T >> 4, g = (T >> 1) & 7, kc = T & 1;
        int l16 = lane & 15, quad = lane >> 4;
        int oc = g * 16 + l16, ic = kc * 32 + quad * 8 + j;
        wb[F] = f2bf(cw[(oc * 64 + ic) * 9 + tap]);
      }
    }
    return;
  }
  __shared__ float W[2048];
  __shared__ float Bias[32];
  const int n = blockIdx.x * 256 + t;
  if (z == 0) {
    for (int i = t; i < 512; i += 256) W[i] = wB[i];
    for (int i = t; i < 512; i += 256) W[512 + i] = wC[i];
    if (t < 8) Bias[t] = bB[t];
    if (t >= 8 && t < 16) Bias[t] = bC[t - 8];
  } else {
    const float* wsrc = wD + (z - 1) * 2048;
    for (int i = t; i < 2048; i += 256) W[i] = wsrc[i];
    if (t < 32) Bias[t] = bD[(z - 1) * 32 + t];
  }
  __syncthreads();
  float xv[64];
#pragma unroll
  for (int c = 0; c < 64; ++c) xv[c] = x[((b * 64 + c) << 12) + n];
  if (z == 0) {
    float o[16];
#pragma unroll
    for (int k = 0; k < 16; ++k) {
      f32x4 s = {0.f, 0.f, 0.f, 0.f};
#pragma unroll
      for (int cq = 0; cq < 16; ++cq) {
        f32x4 wv = *(const f32x4*)&W[k * 64 + cq * 4];
        f32x4 xq = {xv[cq * 4], xv[cq * 4 + 1], xv[cq * 4 + 2], xv[cq * 4 + 3]};
        s += wv * xq;
      }
      o[k] = Bias[k] + s[0] + s[1] + s[2] + s[3];
    }
    int base = ((b << 12) + n) * 8;
    u32x4 pb, pc;
#pragma unroll
    for (int i = 0; i < 4; ++i) {
      // featB pre-scaled by log2(e) so k2 can use raw v_exp_f32 (exp2)
      pb[i] = (unsigned)f2bf(o[2 * i] * LOG2E) | ((unsigned)f2bf(o[2 * i + 1] * LOG2E) << 16);
      pc[i] = (unsigned)f2bf(o[8 + 2 * i]) | ((unsigned)f2bf(o[8 + 2 * i + 1]) << 16);
    }
    *(u32x4*)&featBb[base] = pb;
    *(u32x4*)&featCb[base] = pc;
  } else {
#pragma unroll 4
    for (int k = 0; k < 32; ++k) {
      f32x4 s = {0.f, 0.f, 0.f, 0.f};
#pragma unroll
      for (int cq = 0; cq < 16; ++cq) {
        f32x4 wv = *(const f32x4*)&W[k * 64 + cq * 4];
        f32x4 xq = {xv[cq * 4], xv[cq * 4 + 1], xv[cq * 4 + 2], xv[cq * 4 + 3]};
        s += wv * xq;
      }
      float val = Bias[k] + s[0] + s[1] + s[2] + s[3];
      featD[((b * 64 + (z - 1) * 32 + k) << 12) + n] = f2bf(val);
    }
  }
}

// ---------------- Kernel 2: PAM partial attention, 32x32x16 MFMA, register-resident P.
// R18: RECOVERY. R17's __launch_bounds__(256,4) forced VGPR=64 -> 351MB scratch spill
// (k2 111us, total 257us). Lesson re-learned: k2's live state needs ~130-150 unified
// regs; any forced cap below that = scratch. Plain launch_bounds(256); keep the
// register-lighter R17 body (no accd/onesA den-MFMA, no sn pipeline — both perf-null).
// Keep: Df dbuf issue-early/write-late, afv prefetch, setprio around PV, 1 barrier/iter.
__global__ void __launch_bounds__(256) k2_pam_part(
    const u16* __restrict__ fBb, const u16* __restrict__ fCb, const u16* __restrict__ fD,
    u16* __restrict__ numPart, float* __restrict__ denPart) {
  __shared__ u16 Df[2][64 * 132];  // 33.8 KB
  const int t = threadIdx.x, b = blockIdx.y, z = blockIdx.z;
  const int w = t >> 6, lane = t & 63, l32 = lane & 31, hi = lane >> 5;
  const int nb = blockIdx.x * 128 + w * 32;  // wave's 32-n tile
  const int mz = z << 10;

  // staging coords (loop-invariant): thread covers 4 chunks of Df[64][128]
  int srow[4], smo[4];
#pragma unroll
  for (int hh = 0; hh < 4; ++hh) {
    int idx = hh * 256 + t;
    srow[hh] = idx >> 4;
    smo[hh] = (idx & 15) << 3;
  }

  // Q fragment: B[k][n], lane (n=l32, hi): k = hi*8+j. Real K = 8 -> hi lanes zero.
  bf16x8 bq = (bf16x8)(short)0;
  if (hi == 0) bq = *(const bf16x8*)&fBb[(((b << 12) + nb + l32) << 3)];

  f32x16 acc0 = (f32x16)(0.0f), acc1 = (f32x16)(0.0f);
  float denp = 0.f;

  u32x4 sreg[4];
#define K2_ISSUE(CH) {                                                        \
    int m0_ = mz + ((CH) << 7);                                               \
    _Pragma("unroll")                                                         \
    for (int hh = 0; hh < 4; ++hh)                                            \
      sreg[hh] = *(const u32x4*)&fD[((b * 64 + srow[hh]) << 12) + m0_ + smo[hh]]; }
#define K2_WRITE(BUF) {                                                       \
    _Pragma("unroll")                                                         \
    for (int hh = 0; hh < 4; ++hh)                                            \
      *(u32x4*)&Df[BUF][srow[hh] * 132 + smo[hh]] = sreg[hh]; }

  K2_ISSUE(0);
  K2_WRITE(0);
  __syncthreads();

#pragma unroll 2
  for (int ch = 0; ch < 8; ++ch) {
    const int cur = ch & 1;
    const int m0 = mz + (ch << 7);
    if (ch < 7) K2_ISSUE(ch + 1);  // next tile: global -> regs, lands under compute

    // prefetch af (fCb) for all 4 mt2: off the S critical path
    bf16x8 afv[4];
#pragma unroll
    for (int mt2 = 0; mt2 < 4; ++mt2) {
      bf16x8 a = (bf16x8)(short)0;
      if (hi == 0) a = *(const bf16x8*)&fCb[(((b << 12) + m0 + mt2 * 32 + l32) << 3)];
      afv[mt2] = a;
    }

#pragma unroll
    for (int mt2 = 0; mt2 < 4; ++mt2) {
      // S = K.Q^T (32x32): lane (n=l32,hi), reg r: m = (r&3)+8*(r>>2)+4*hi
      f32x16 sc = __builtin_amdgcn_mfma_f32_32x32x16_bf16(afv[mt2], bq, (f32x16)(0.0f), 0, 0, 0);
      // exp, den-sum, pack bf16 pairs
      unsigned u0[8];
      float dsum = 0.f;
#pragma unroll
      for (int i = 0; i < 8; ++i) {
        float e0 = FAST_EXP2(sc[2 * i]);
        float e1 = FAST_EXP2(sc[2 * i + 1]);
        dsum += e0 + e1;
        u0[i] = __builtin_amdgcn_perm(__float_as_uint(e1), __float_as_uint(e0), 0x07060302u);
      }
      denp += dsum;
      // Rearrange to PV B-frag: for kc, reg p: pair(m = kc*16 + hi*8 + 2p)
      permswap32(u0[0], u0[2]); permswap32(u0[1], u0[3]);
      permswap32(u0[4], u0[6]); permswap32(u0[5], u0[7]);

      // PV: out[c,n] += D[c,m]*P[n,m]
      __builtin_amdgcn_s_setprio(1);
#pragma unroll
      for (int kc = 0; kc < 2; ++kc) {
        u32x4 q0 = {u0[4 * kc], u0[4 * kc + 1], u0[4 * kc + 2], u0[4 * kc + 3]};
        bf16x8 bv0 = *(bf16x8*)&q0;
        bf16x8 av0 = *(const bf16x8*)&Df[cur][(l32) * 132 + mt2 * 32 + kc * 16 + hi * 8];
        bf16x8 av1 = *(const bf16x8*)&Df[cur][(32 + l32) * 132 + mt2 * 32 + kc * 16 + hi * 8];
        acc0 = __builtin_amdgcn_mfma_f32_32x32x16_bf16(av0, bv0, acc0, 0, 0, 0);
        acc1 = __builtin_amdgcn_mfma_f32_32x32x16_bf16(av1, bv0, acc1, 0, 0, 0);
      }
      __builtin_amdgcn_s_setprio(0);
    }

    if (ch < 7) K2_WRITE(cur ^ 1);  // safe: buf cur^1 last read before prev barrier
    __syncthreads();
  }
#undef K2_ISSUE
#undef K2_WRITE

  const int zb = z * 8 + b;
#pragma unroll
  for (int r = 0; r < 16; ++r) {
    int c = (r & 3) + ((r >> 2) << 3) + (hi << 2);
    numPart[((zb * 64 + c) << 12) + nb + l32] = (u16)(__float_as_uint(acc0[r]) >> 16);
    numPart[((zb * 64 + c + 32) << 12) + nb + l32] = (u16)(__float_as_uint(acc1[r]) >> 16);
  }
  {
    float d = denp + __shfl_xor(denp, 32);
    if (hi == 0) denPart[(zb << 12) + nb + l32] = d;
  }
}

// ---------------- Kernel 3: reduce PAM partials -> x1 (global + LDS), then CAM gram partials
__global__ void __launch_bounds__(256) k3_gram(
    const u16* __restrict__ numPart, const float* __restrict__ denPart,
    const float* __restrict__ x, const float* __restrict__ alpha,
    float* __restrict__ x1, float* __restrict__ attPart) {
  __shared__ float X[64 * 132];
  __shared__ float Dinv[128];
  const int t = threadIdx.x, b = blockIdx.y, cx = blockIdx.x;
  const int n0 = cx * 128;
  if (t < 128) {
    float den = 0.f;
#pragma unroll
    for (int z = 0; z < 4; ++z) den += denPart[(((z * 8 + b) << 12)) + n0 + t];
    Dinv[t] = alpha[0] / den;
  }
  __syncthreads();
  for (int idx = t; idx < 4096; idx += 256) {
    int row = idx >> 6, cp = (idx & 63) * 2;
    int gi = ((b * 64 + row) << 12) + n0 + cp;
    float num0 = 0.f, num1 = 0.f;
#pragma unroll
    for (int z = 0; z < 4; ++z) {
      unsigned v = *(const unsigned*)&numPart[(((z * 8 + b) * 64 + row) << 12) + n0 + cp];
      num0 += __uint_as_float(v << 16);
      num1 += __uint_as_float(v & 0xFFFF0000u);
    }
    float v0 = num0 * Dinv[cp] + x[gi];
    float v1 = num1 * Dinv[cp + 1] + x[gi + 1];
    X[row * 132 + cp] = v0;
    X[row * 132 + cp + 1] = v1;
    x1[gi] = v0;
    x1[gi + 1] = v1;
  }
  __syncthreads();
  const int cg = t >> 4, dg = t & 15;
  f32x4 acc[4][4];
#pragma unroll
  for (int i = 0; i < 4; ++i)
#pragma unroll
    for (int k = 0; k < 4; ++k) acc[i][k] = (f32x4){0.f, 0.f, 0.f, 0.f};
  for (int nq0 = 0; nq0 < 32; ++nq0) {
    int nq = (nq0 + dg) & 31;
    f32x4 a[4], bb[4];
#pragma unroll
    for (int i = 0; i < 4; ++i) a[i] = *(const f32x4*)&X[(cg * 4 + i) * 132 + nq * 4];
#pragma unroll
    for (int k = 0; k < 4; ++k) bb[k] = *(const f32x4*)&X[(dg * 4 + k) * 132 + nq * 4];
#pragma unroll
    for (int i = 0; i < 4; ++i)
#pragma unroll
      for (int k = 0; k < 4; ++k) acc[i][k] += a[i] * bb[k];
  }
#pragma unroll
  for (int i = 0; i < 4; ++i)
#pragma unroll
    for (int k = 0; k < 4; ++k) {
      f32x4 s = acc[i][k];
      attPart[((b * 32 + cx) * 64 + cg * 4 + i) * 64 + dg * 4 + k] = s[0] + s[1] + s[2] + s[3];
    }
}

// ---------------- Kernel 4: CAM softmax (min-form), one wave per c-row. grid (16, 8)
__global__ void __launch_bounds__(256) k4_softmax(const float* __restrict__ attPart, float* __restrict__ attP) {
  const int b = blockIdx.y, t = threadIdx.x;
  const int c = (blockIdx.x << 2) + (t >> 6), d = t & 63;
  float v = 0.f;
  for (int p = 0; p < 32; ++p) v += attPart[((b * 32 + p) * 64 + c) * 64 + d];
  float mn = v;
#pragma unroll
  for (int off = 1; off < 64; off <<= 1) mn = fminf(mn, __shfl_xor(mn, off));
  float e = __expf(mn - v);
  float sum = e;
#pragma unroll
  for (int off = 1; off < 64; off <<= 1) sum += __shfl_xor(sum, off);
  attP[(b * 64 + c) * 64 + d] = e / sum;
}

// ---------------- Kernel 5: x2 = beta*(attP @ x1) + x1, bf16 NHWC.
// grid (64,8): thread = (n, c-quad), 16 scalar accs, x1 streamed from L2.
__global__ void __launch_bounds__(256) k5_apply(
    const float* __restrict__ attP, const float* __restrict__ x1,
    const float* __restrict__ beta, u16* __restrict__ x2b) {
  __shared__ float A[64 * 68];
  const int t = threadIdx.x, b = blockIdx.y;
  for (int idx = t; idx < 4096; idx += 256) A[(idx >> 6) * 68 + (idx & 63)] = attP[(b << 12) + idx];
  __syncthreads();
  const int n = blockIdx.x * 64 + (t & 63);
  const int cq = t >> 6;
  const float bv = beta[0];
  float acc[16];
#pragma unroll
  for (int i = 0; i < 16; ++i) acc[i] = 0.f;
  const float* xcol = x1 + ((size_t)b << 18) + n;
#pragma unroll 4
  for (int dq = 0; dq < 16; ++dq) {
    float x0 = xcol[(size_t)(dq * 4 + 0) << 12];
    float x1v = xcol[(size_t)(dq * 4 + 1) << 12];
    float x2 = xcol[(size_t)(dq * 4 + 2) << 12];
    float x3 = xcol[(size_t)(dq * 4 + 3) << 12];
#pragma unroll
    for (int i = 0; i < 16; ++i) {
      const float* av = &A[(cq * 16 + i) * 68 + dq * 4];
      acc[i] += av[0] * x0 + av[1] * x1v + av[2] * x2 + av[3] * x3;
    }
  }
  u16* orow = x2b + ((((size_t)(b << 12) + n) << 6) + cq * 16);
  unsigned pk[8];
#pragma unroll
  for (int i = 0; i < 16; i += 2) {
    float v0 = bv * acc[i] + xcol[(size_t)(cq * 16 + i) << 12];
    float v1 = bv * acc[i + 1] + xcol[(size_t)(cq * 16 + i + 1) << 12];
    pk[i >> 1] = (unsigned)f2bf(v0) | ((unsigned)f2bf(v1) << 16);
  }
  *(u32x4*)&orow[0] = *(u32x4*)&pk[0];
  *(u32x4*)&orow[8] = *(u32x4*)&pk[4];
}

// ---------------- Kernel 6: conv3x3 bf16 MFMA, lane-linear weight tiles.
// Fused BN partial stats: per-(b,h)-block partial sum/sumsq -> private slot
// pstat2[(oc*2+st)*512 + b*64+h]; k8 reduces the 512 partials per channel.
__global__ void __launch_bounds__(256) k6_mfma(const u16* __restrict__ x2b, const u16* __restrict__ wb,
                                               float* __restrict__ y, float* __restrict__ pstat2) {
  __shared__ u16 Xl[3 * 66 * 72];
  __shared__ float pp[4][64][2];
  const int t = threadIdx.x, b = blockIdx.y, h = blockIdx.x;
  for (int idx = t; idx < 3 * 66 * 8; idx += 256) {
    int r = idx / 528;
    int rem = idx - r * 528;
    int c = rem >> 3, icq = rem & 7;
    int gy = h - 1 + r, gx = c - 1;
    u32x4 v = {0u, 0u, 0u, 0u};
    if (gy >= 0 && gy < 64 && gx >= 0 && gx < 64)
      v = *(const u32x4*)&x2b[(((size_t)(b << 6 | gy) << 6) + gx) * 64 + icq * 8];
    *(u32x4*)&Xl[(r * 66 + c) * 72 + icq * 8] = v;
  }
  __syncthreads();
  const int w = t >> 6, lane = t & 63, quad = lane >> 4, l16 = lane & 15;
  const int mBase = (w & 1) * 64;
  const int og = (w & 1) * 4;
  const int nBase = (w >> 1) * 32;
  f32x4 acc[4][2];
#pragma unroll
  for (int ot = 0; ot < 4; ++ot)
#pragma unroll
    for (int nt = 0; nt < 2; ++nt) acc[ot][nt] = (f32x4){0.f, 0.f, 0.f, 0.f};
#pragma unroll 3
  for (int tap = 0; tap < 9; ++tap) {
    const int dy = tap / 3, dx = tap - dy * 3;
    bf16x8 af[4][2];
#pragma unroll
    for (int ot = 0; ot < 4; ++ot)
#pragma unroll
      for (int kc = 0; kc < 2; ++kc)
        af[ot][kc] = *(const bf16x8*)&wb[((((tap * 8 + og + ot) * 2 + kc) << 6) + lane) << 3];
#pragma unroll
    for (int nt = 0; nt < 2; ++nt) {
      const int prow = dy * 66 + nBase + nt * 16 + l16 + dx;
#pragma unroll
      for (int kc = 0; kc < 2; ++kc) {
        bf16x8 bv = *(const bf16x8*)&Xl[prow * 72 + kc * 32 + quad * 8];
#pragma unroll
        for (int ot = 0; ot < 4; ++ot)
          acc[ot][nt] = __builtin_amdgcn_mfma_f32_16x16x32_bf16(af[ot][kc], bv, acc[ot][nt], 0, 0, 0);
      }
    }
  }
#pragma unroll
  for (int ot = 0; ot < 4; ++ot)
#pragma unroll
    for (int nt = 0; nt < 2; ++nt)
#pragma unroll
      for (int r = 0; r < 4; ++r) {
        int oc = mBase + ot * 16 + quad * 4 + r;
        int pix = nBase + nt * 16 + l16;
        y[((b * 128 + oc) << 12) + (h << 6) + pix] = acc[ot][nt][r];
      }
  // ---- fused BN partial stats
  float bs[4][4], bss[4][4];
#pragma unroll
  for (int ot = 0; ot < 4; ++ot)
#pragma unroll
    for (int r = 0; r < 4; ++r) {
      float v0 = acc[ot][0][r], v1 = acc[ot][1][r];
      bs[ot][r] = v0 + v1;
      bss[ot][r] = v0 * v0 + v1 * v1;
    }
#pragma unroll
  for (int off = 1; off < 16; off <<= 1) {
#pragma unroll
    for (int ot = 0; ot < 4; ++ot)
#pragma unroll
      for (int r = 0; r < 4; ++r) {
        bs[ot][r] += __shfl_xor(bs[ot][r], off);
        bss[ot][r] += __shfl_xor(bss[ot][r], off);
      }
  }
  if (l16 == 0) {
#pragma unroll
    for (int ot = 0; ot < 4; ++ot)
#pragma unroll
      for (int r = 0; r < 4; ++r) {
        int ocl = ot * 16 + quad * 4 + r;
        pp[w][ocl][0] = bs[ot][r];
        pp[w][ocl][1] = bss[ot][r];
      }
  }
  __syncthreads();
  {
    int oc = t >> 1, st = t & 1;
    float v = (oc < 64) ? (pp[0][oc][st] + pp[2][oc][st])
                        : (pp[1][oc - 64][st] + pp[3][oc - 64][st]);
    pstat2[(oc * 2 + st) * 512 + (b << 6) + h] = v;
  }
}

// ---------------- Kernel 8: BN finalize (from k6's 512 per-block partials) + ReLU + maxpool
__global__ void __launch_bounds__(256) k8_pool(const float* __restrict__ y, const float* __restrict__ pstat2,
                                               const float* __restrict__ gamma, const float* __restrict__ bbeta,
                                               float* __restrict__ out) {
  const int bc = blockIdx.x;
  const int ch = bc & 127;
  float s = 0.f, ss = 0.f;
  for (int i = threadIdx.x; i < 512; i += 256) {
    s += pstat2[ch * 1024 + i];
    ss += pstat2[ch * 1024 + 512 + i];
  }
#pragma unroll
  for (int off = 1; off < 64; off <<= 1) { s += __shfl_xor(s, off); ss += __shfl_xor(ss, off); }
  __shared__ float rs[4], rss[4];
  if ((threadIdx.x & 63) == 0) { rs[threadIdx.x >> 6] = s; rss[threadIdx.x >> 6] = ss; }
  __syncthreads();
  const float S = rs[0] + rs[1] + rs[2] + rs[3];
  const float SS = rss[0] + rss[1] + rss[2] + rss[3];
  const float mean = S * (1.f / 32768.f);
  const float var = SS * (1.f / 32768.f) - mean * mean;
  const float sc = gamma[ch] * rsqrtf(var + 1e-5f);
  const float sh = bbeta[ch] - mean * sc;
  const float* p = y + (bc << 12);
  float* op = out + bc * (33 * 32);
  for (int i = threadIdx.x; i < 33 * 32; i += 256) {
    int oh = i >> 5, ow = i & 31;
    int r0 = 2 * oh - 1, r1 = 2 * oh;
    float m = 0.f;
    if (r0 >= 0) {
      m = fmaxf(m, p[r0 * 64 + 2 * ow] * sc + sh);
      m = fmaxf(m, p[r0 * 64 + 2 * ow + 1] * sc + sh);
    }
    if (r1 <= 63) {
      m = fmaxf(m, p[r1 * 64 + 2 * ow] * sc + sh);
      m = fmaxf(m, p[r1 * 64 + 2 * ow + 1] * sc + sh);
    }
    op[i] = m;
  }
}

extern "C" void kernel_launch(void* const* d_in, const int* in_sizes, int n_in,
                              void* d_out, int out_size, void* d_ws, size_t ws_size,
                              hipStream_t stream) {
  const float* x      = (const float*)d_in[0];
  const float* wB     = (const float*)d_in[1];
  const float* bB     = (const float*)d_in[2];
  const float* wC     = (const float*)d_in[3];
  const float* bC     = (const float*)d_in[4];
  const float* wD     = (const float*)d_in[5];
  const float* bD     = (const float*)d_in[6];
  const float* alpha  = (const float*)d_in[7];
  const float* beta   = (const float*)d_in[8];
  const float* cw     = (const float*)d_in[9];
  const float* gamma  = (const float*)d_in[11];
  const float* bnbeta = (const float*)d_in[12];

  // Workspace overlays (35.3 MB):
  //  [0,4M):      featBb/featCb/fDb [k1..k2p]  then x2b [k5..k6]
  //  [5M,13M):    x1 [k3..k5]
  //  [13M,29.8M): numPart [k2p..k3]  then y [k6..k8]
  //  [29.0M+..]:  denPart, attPart (reused as pstat2 after k4), attP, wb
  char* ws = (char*)d_ws;
  u16*   featBb  = (u16*)  (ws + 0);          // 512 KB
  u16*   featCb  = (u16*)  (ws + 524288);     // 512 KB
  u16*   fDb     = (u16*)  (ws + 1048576);    // 4 MB
  u16*   x2b     = (u16*)  (ws + 0);          // 4 MB (bf16 NHWC) — over feat*
  float* x1      = (float*)(ws + 5242880);    // 8 MB
  u16*   numPart = (u16*)  (ws + 13631488);   // 16 MB
  float* y       = (float*)(ws + 13631488);   // 16 MB — over numPart
  float* denPart = (float*)(ws + 30408704);   // 512 KB
  float* attPart = (float*)(ws + 30932992);   // 4 MB
  float* pstat2  = (float*)(ws + 30932992);   // 512 KB — over attPart (dead after k4)
  float* attP    = (float*)(ws + 35127296);   // 128 KB
  u16*   wb      = (u16*)  (ws + 35258368);   // 144 KB
  float* pstats  = (float*)(ws + 35405824);   // 4 KB (unused)
  float* outp    = (float*)d_out;
  (void)pstats;

  k1_conv1x1<<<dim3(16, 8, 4), 256, 0, stream>>>(x, wB, bB, wC, bC, wD, bD, featBb, featCb, fDb, cw, wb);
  k2_pam_part<<<dim3(32, 8, 4), 256, 0, stream>>>(featBb, featCb, fDb, numPart, denPart);
  k3_gram<<<dim3(32, 8), 256, 0, stream>>>(numPart, denPart, x, alpha, x1, attPart);
  k4_softmax<<<dim3(16, 8), 256, 0, stream>>>(attPart, attP);
  k5_apply<<<dim3(64, 8), 256, 0, stream>>>(attP, x1, beta, x2b);
  k6_mfma<<<dim3(64, 8), 256, 0, stream>>>(x2b, wb, y, pstat2);
  k8_pool<<<dim3(1024), 256, 0, stream>>>(y, pstat2, gamma, bnbeta, outp);
}

// Round 8
// 180.451 us; speedup vs baseline: 1.4273x; 1.0357x over previous
//
#include <hip/hip_runtime.h>

using f32x4  = __attribute__((ext_vector_type(4))) float;
using f32x16 = __attribute__((ext_vector_type(16))) float;
using bf16x8 = __attribute__((ext_vector_type(8))) short;
using u32x4  = __attribute__((ext_vector_type(4))) unsigned int;
using u32x2  = __attribute__((ext_vector_type(2))) unsigned int;
typedef unsigned short u16;

__device__ __forceinline__ u16 f2bf(float f) {
  unsigned u = __float_as_uint(f);
  unsigned r = (u + 0x7FFFu + ((u >> 16) & 1u)) >> 16;
  return (u16)r;
}

// exp2 path: featB is pre-scaled by log2(e) in k1, so exp(s) == exp2(s_scaled).
#if __has_builtin(__builtin_amdgcn_exp2f)
#define FAST_EXP2(x) __builtin_amdgcn_exp2f(x)
#else
#define FAST_EXP2(x) __expf(0.6931471805599453f * (x))
#endif

#define LOG2E 1.4426950408889634f

// a' = {a.lo32lanes, b.lo32lanes}; b' = {a.hi32lanes, b.hi32lanes}
__device__ __forceinline__ void permswap32(unsigned& a, unsigned& b) {
  asm volatile("v_permlane32_swap_b32 %0, %1" : "+v"(a), "+v"(b));
}

// ---------------- Kernel 1: 1x1 convs (+ z=3: conv3x3 weight cvt -> lane-linear MFMA tiles)
__global__ void __launch_bounds__(256) k1_conv1x1(
    const float* __restrict__ x, const float* __restrict__ wB, const float* __restrict__ bB,
    const float* __restrict__ wC, const float* __restrict__ bC,
    const float* __restrict__ wD, const float* __restrict__ bD,
    u16* __restrict__ featBb, u16* __restrict__ featCb, u16* __restrict__ featD,
    const float* __restrict__ cw, u16* __restrict__ wb) {
  const int t = threadIdx.x;
  const int b = blockIdx.y;
  const int z = blockIdx.z;
  if (z == 3) {
    int gid = (b * 16 + blockIdx.x) * 256 + t;
#pragma unroll
    for (int k = 0; k < 3; ++k) {
      int F = gid + k * 32768;
      if (F < 73728) {
        int j = F & 7, lane = (F >> 3) & 63, T = F >> 9;
        int tap = T >> 4, g = (T >> 1) & 7, kc = T & 1;
        int l16 = lane & 15, quad = lane >> 4;
        int oc = g * 16 + l16, ic = kc * 32 + quad * 8 + j;
        wb[F] = f2bf(cw[(oc * 64 + ic) * 9 + tap]);
      }
    }
    return;
  }
  __shared__ float W[2048];
  __shared__ float Bias[32];
  const int n = blockIdx.x * 256 + t;
  if (z == 0) {
    for (int i = t; i < 512; i += 256) W[i] = wB[i];
    for (int i = t; i < 512; i += 256) W[512 + i] = wC[i];
    if (t < 8) Bias[t] = bB[t];
    if (t >= 8 && t < 16) Bias[t] = bC[t - 8];
  } else {
    const float* wsrc = wD + (z - 1) * 2048;
    for (int i = t; i < 2048; i += 256) W[i] = wsrc[i];
    if (t < 32) Bias[t] = bD[(z - 1) * 32 + t];
  }
  __syncthreads();
  float xv[64];
#pragma unroll
  for (int c = 0; c < 64; ++c) xv[c] = x[((b * 64 + c) << 12) + n];
  if (z == 0) {
    float o[16];
#pragma unroll
    for (int k = 0; k < 16; ++k) {
      f32x4 s = {0.f, 0.f, 0.f, 0.f};
#pragma unroll
      for (int cq = 0; cq < 16; ++cq) {
        f32x4 wv = *(const f32x4*)&W[k * 64 + cq * 4];
        f32x4 xq = {xv[cq * 4], xv[cq * 4 + 1], xv[cq * 4 + 2], xv[cq * 4 + 3]};
        s += wv * xq;
      }
      o[k] = Bias[k] + s[0] + s[1] + s[2] + s[3];
    }
    int base = ((b << 12) + n) * 8;
    u32x4 pb, pc;
#pragma unroll
    for (int i = 0; i < 4; ++i) {
      // featB pre-scaled by log2(e) so k2 can use raw v_exp_f32 (exp2)
      pb[i] = (unsigned)f2bf(o[2 * i] * LOG2E) | ((unsigned)f2bf(o[2 * i + 1] * LOG2E) << 16);
      pc[i] = (unsigned)f2bf(o[8 + 2 * i]) | ((unsigned)f2bf(o[8 + 2 * i + 1]) << 16);
    }
    *(u32x4*)&featBb[base] = pb;
    *(u32x4*)&featCb[base] = pc;
  } else {
#pragma unroll 4
    for (int k = 0; k < 32; ++k) {
      f32x4 s = {0.f, 0.f, 0.f, 0.f};
#pragma unroll
      for (int cq = 0; cq < 16; ++cq) {
        f32x4 wv = *(const f32x4*)&W[k * 64 + cq * 4];
        f32x4 xq = {xv[cq * 4], xv[cq * 4 + 1], xv[cq * 4 + 2], xv[cq * 4 + 3]};
        s += wv * xq;
      }
      float val = Bias[k] + s[0] + s[1] + s[2] + s[3];
      featD[((b * 64 + (z - 1) * 32 + k) << 12) + n] = f2bf(val);
    }
  }
}

// ---------------- Kernel 2: PAM partial attention — R16 body (best measured: 43.6us).
// accd/onesA den on MFMA pipe (+~2us vs VALU dsum, R18 A/B), 2-deep S pipeline,
// setprio around PV, Df dbuf issue-early/write-late, 1 barrier/iter. NO min-waves
// launch_bounds (R11/R17: forced caps below ~140 unified regs -> scratch spill).
__global__ void __launch_bounds__(256) k2_pam_part(
    const u16* __restrict__ fBb, const u16* __restrict__ fCb, const u16* __restrict__ fD,
    u16* __restrict__ numPart, float* __restrict__ denPart) {
  __shared__ u16 Df[2][64 * 132];  // 33.8 KB
  const int t = threadIdx.x, b = blockIdx.y, z = blockIdx.z;
  const int w = t >> 6, lane = t & 63, l32 = lane & 31, hi = lane >> 5;
  const int nb = blockIdx.x * 128 + w * 32;  // wave's 32-n tile
  const int mz = z << 10;

  // staging coords (loop-invariant): thread covers 4 chunks of Df[64][128]
  int srow[4], smo[4];
#pragma unroll
  for (int hh = 0; hh < 4; ++hh) {
    int idx = hh * 256 + t;
    srow[hh] = idx >> 4;
    smo[hh] = (idx & 15) << 3;
  }

  // Q fragment: B[k][n], lane (n=l32, hi): k = hi*8+j. Real K = 8 -> hi lanes zero.
  bf16x8 bq = (bf16x8)(short)0;
  if (hi == 0) bq = *(const bf16x8*)&fBb[(((b << 12) + nb + l32) << 3)];

  // ones-row A fragment: A[c][k], lane (c=l32, hi). Row c==0 all-ones -> accd row 0 = den.
  bf16x8 onesA = (bf16x8)(short)0;
  if (l32 == 0) onesA = (bf16x8)(short)0x3F80;

  f32x16 acc0 = (f32x16)(0.0f), acc1 = (f32x16)(0.0f), accd = (f32x16)(0.0f);

  u32x4 sreg[4];
#define K2_ISSUE(CH) {                                                        \
    int m0_ = mz + ((CH) << 7);                                               \
    _Pragma("unroll")                                                         \
    for (int hh = 0; hh < 4; ++hh)                                            \
      sreg[hh] = *(const u32x4*)&fD[((b * 64 + srow[hh]) << 12) + m0_ + smo[hh]]; }
#define K2_WRITE(BUF) {                                                       \
    _Pragma("unroll")                                                         \
    for (int hh = 0; hh < 4; ++hh)                                            \
      *(u32x4*)&Df[BUF][srow[hh] * 132 + smo[hh]] = sreg[hh]; }

  K2_ISSUE(0);
  K2_WRITE(0);
  __syncthreads();

#pragma unroll 2
  for (int ch = 0; ch < 8; ++ch) {
    const int cur = ch & 1;
    const int m0 = mz + (ch << 7);
    if (ch < 7) K2_ISSUE(ch + 1);  // next tile: global -> regs, lands under compute

    // prefetch af (fCb) for all 4 mt2: off the S critical path
    bf16x8 afv[4];
#pragma unroll
    for (int mt2 = 0; mt2 < 4; ++mt2) {
      bf16x8 a = (bf16x8)(short)0;
      if (hi == 0) a = *(const bf16x8*)&fCb[(((b << 12) + m0 + mt2 * 32 + l32) << 3)];
      afv[mt2] = a;
    }

    // 2-deep S pipeline: S[mt2+1] issues before exp/PV of S[mt2]
    f32x16 sc = __builtin_amdgcn_mfma_f32_32x32x16_bf16(afv[0], bq, (f32x16)(0.0f), 0, 0, 0);
#pragma unroll
    for (int mt2 = 0; mt2 < 4; ++mt2) {
      f32x16 sn;
      if (mt2 < 3) sn = __builtin_amdgcn_mfma_f32_32x32x16_bf16(afv[mt2 + 1], bq, (f32x16)(0.0f), 0, 0, 0);
      // exp, pack bf16 pairs. Lane (n=l32,hi), reg r: m = (r&3)+8*(r>>2)+4*hi.
      unsigned u0[8];
#pragma unroll
      for (int i = 0; i < 8; ++i) {
        float e0 = FAST_EXP2(sc[2 * i]);
        float e1 = FAST_EXP2(sc[2 * i + 1]);
        u0[i] = __builtin_amdgcn_perm(__float_as_uint(e1), __float_as_uint(e0), 0x07060302u);
      }
      // Rearrange to PV B-frag: for kc, reg p: pair(m = kc*16 + hi*8 + 2p)
      permswap32(u0[0], u0[2]); permswap32(u0[1], u0[3]);
      permswap32(u0[4], u0[6]); permswap32(u0[5], u0[7]);

      // PV: out[c,n] += D[c,m]*P[n,m]; den row via onesA on the MFMA pipe
      __builtin_amdgcn_s_setprio(1);
#pragma unroll
      for (int kc = 0; kc < 2; ++kc) {
        u32x4 q0 = {u0[4 * kc], u0[4 * kc + 1], u0[4 * kc + 2], u0[4 * kc + 3]};
        bf16x8 bv0 = *(bf16x8*)&q0;
        bf16x8 av0 = *(const bf16x8*)&Df[cur][(l32) * 132 + mt2 * 32 + kc * 16 + hi * 8];
        bf16x8 av1 = *(const bf16x8*)&Df[cur][(32 + l32) * 132 + mt2 * 32 + kc * 16 + hi * 8];
        acc0 = __builtin_amdgcn_mfma_f32_32x32x16_bf16(av0, bv0, acc0, 0, 0, 0);
        acc1 = __builtin_amdgcn_mfma_f32_32x32x16_bf16(av1, bv0, acc1, 0, 0, 0);
        accd = __builtin_amdgcn_mfma_f32_32x32x16_bf16(onesA, bv0, accd, 0, 0, 0);
      }
      __builtin_amdgcn_s_setprio(0);
      if (mt2 < 3) sc = sn;
    }

    if (ch < 7) K2_WRITE(cur ^ 1);  // safe: buf cur^1 last read before prev barrier
    __syncthreads();
  }
#undef K2_ISSUE
#undef K2_WRITE

  const int zb = z * 8 + b;
#pragma unroll
  for (int r = 0; r < 16; ++r) {
    int c = (r & 3) + ((r >> 2) << 3) + (hi << 2);
    numPart[((zb * 64 + c) << 12) + nb + l32] = (u16)(__float_as_uint(acc0[r]) >> 16);
    numPart[((zb * 64 + c + 32) << 12) + nb + l32] = (u16)(__float_as_uint(acc1[r]) >> 16);
  }
  // den: accd row c=0 -> reg 0 on hi==0 lanes, n = l32
  if (hi == 0) denPart[(zb << 12) + nb + l32] = accd[0];
}

// ---------------- Kernel 3: reduce PAM partials -> x1, then CAM gram partials.
// R19: grid (32,8,2) — z-halves split gram c-rows (was 256 blocks = 1/CU = 12.5%
// occupancy cap, latency-exposed). Both z build the X tile (num-reduce duplicated,
// +16MB L2 read — free at 10% HBM); z=0 writes x1. Thread: acc[2][4], c = zz*32+cg*2+i.
__global__ void __launch_bounds__(256) k3_gram(
    const u16* __restrict__ numPart, const float* __restrict__ denPart,
    const float* __restrict__ x, const float* __restrict__ alpha,
    float* __restrict__ x1, float* __restrict__ attPart) {
  __shared__ float X[64 * 132];
  __shared__ float Dinv[128];
  const int t = threadIdx.x, b = blockIdx.y, cx = blockIdx.x, zz = blockIdx.z;
  const int n0 = cx * 128;
  if (t < 128) {
    float den = 0.f;
#pragma unroll
    for (int z = 0; z < 4; ++z) den += denPart[(((z * 8 + b) << 12)) + n0 + t];
    Dinv[t] = alpha[0] / den;
  }
  __syncthreads();
  for (int idx = t; idx < 4096; idx += 256) {
    int row = idx >> 6, cp = (idx & 63) * 2;
    int gi = ((b * 64 + row) << 12) + n0 + cp;
    float num0 = 0.f, num1 = 0.f;
#pragma unroll
    for (int z = 0; z < 4; ++z) {
      unsigned v = *(const unsigned*)&numPart[(((z * 8 + b) * 64 + row) << 12) + n0 + cp];
      num0 += __uint_as_float(v << 16);
      num1 += __uint_as_float(v & 0xFFFF0000u);
    }
    float v0 = num0 * Dinv[cp] + x[gi];
    float v1 = num1 * Dinv[cp + 1] + x[gi + 1];
    X[row * 132 + cp] = v0;
    X[row * 132 + cp + 1] = v1;
    if (zz == 0) {
      x1[gi] = v0;
      x1[gi + 1] = v1;
    }
  }
  __syncthreads();
  const int cg = t >> 4, dg = t & 15;
  const int cbase = zz * 32 + cg * 2;
  f32x4 acc[2][4];
#pragma unroll
  for (int i = 0; i < 2; ++i)
#pragma unroll
    for (int k = 0; k < 4; ++k) acc[i][k] = (f32x4){0.f, 0.f, 0.f, 0.f};
  for (int nq0 = 0; nq0 < 32; ++nq0) {
    int nq = (nq0 + dg) & 31;
    f32x4 a[2], bb[4];
#pragma unroll
    for (int i = 0; i < 2; ++i) a[i] = *(const f32x4*)&X[(cbase + i) * 132 + nq * 4];
#pragma unroll
    for (int k = 0; k < 4; ++k) bb[k] = *(const f32x4*)&X[(dg * 4 + k) * 132 + nq * 4];
#pragma unroll
    for (int i = 0; i < 2; ++i)
#pragma unroll
      for (int k = 0; k < 4; ++k) acc[i][k] += a[i] * bb[k];
  }
#pragma unroll
  for (int i = 0; i < 2; ++i)
#pragma unroll
    for (int k = 0; k < 4; ++k) {
      f32x4 s = acc[i][k];
      attPart[((b * 32 + cx) * 64 + cbase + i) * 64 + dg * 4 + k] = s[0] + s[1] + s[2] + s[3];
    }
}

// ---------------- Kernel 4: CAM softmax (min-form). R19: grid (64,8) x 64 threads —
// one wave per block; 512 blocks cover all 256 CUs (was 128 blocks = half chip idle).
__global__ void __launch_bounds__(64) k4_softmax(const float* __restrict__ attPart, float* __restrict__ attP) {
  const int b = blockIdx.y, c = blockIdx.x, d = threadIdx.x;
  float v = 0.f;
  for (int p = 0; p < 32; ++p) v += attPart[((b * 32 + p) * 64 + c) * 64 + d];
  float mn = v;
#pragma unroll
  for (int off = 1; off < 64; off <<= 1) mn = fminf(mn, __shfl_xor(mn, off));
  float e = __expf(mn - v);
  float sum = e;
#pragma unroll
  for (int off = 1; off < 64; off <<= 1) sum += __shfl_xor(sum, off);
  attP[(b * 64 + c) * 64 + d] = e / sum;
}

// ---------------- Kernel 5: x2 = beta*(attP @ x1) + x1, bf16 NHWC.
// R19: grid (128,8) — thread = (n of 32, c-octet), 8 scalar accs, one u32x4 store.
// x1 L2-read duplication 8x (~64MB L2 ≈ 2us) buys 2x block parallelism.
__global__ void __launch_bounds__(256) k5_apply(
    const float* __restrict__ attP, const float* __restrict__ x1,
    const float* __restrict__ beta, u16* __restrict__ x2b) {
  __shared__ float A[64 * 68];
  const int t = threadIdx.x, b = blockIdx.y;
  for (int idx = t; idx < 4096; idx += 256) A[(idx >> 6) * 68 + (idx & 63)] = attP[(b << 12) + idx];
  __syncthreads();
  const int n = blockIdx.x * 32 + (t & 31);
  const int cq = t >> 5;  // 0..7
  const float bv = beta[0];
  float acc[8];
#pragma unroll
  for (int i = 0; i < 8; ++i) acc[i] = 0.f;
  const float* xcol = x1 + ((size_t)b << 18) + n;
#pragma unroll 4
  for (int dq = 0; dq < 16; ++dq) {
    float x0 = xcol[(size_t)(dq * 4 + 0) << 12];
    float x1v = xcol[(size_t)(dq * 4 + 1) << 12];
    float x2 = xcol[(size_t)(dq * 4 + 2) << 12];
    float x3 = xcol[(size_t)(dq * 4 + 3) << 12];
#pragma unroll
    for (int i = 0; i < 8; ++i) {
      const float* av = &A[(cq * 8 + i) * 68 + dq * 4];
      acc[i] += av[0] * x0 + av[1] * x1v + av[2] * x2 + av[3] * x3;
    }
  }
  u16* orow = x2b + ((((size_t)(b << 12) + n) << 6) + cq * 8);
  unsigned pk[4];
#pragma unroll
  for (int i = 0; i < 8; i += 2) {
    float v0 = bv * acc[i] + xcol[(size_t)(cq * 8 + i) << 12];
    float v1 = bv * acc[i + 1] + xcol[(size_t)(cq * 8 + i + 1) << 12];
    pk[i >> 1] = (unsigned)f2bf(v0) | ((unsigned)f2bf(v1) << 16);
  }
  *(u32x4*)&orow[0] = (u32x4){pk[0], pk[1], pk[2], pk[3]};
}

// ---------------- Kernel 6: conv3x3 bf16 MFMA, lane-linear weight tiles.
// Fused BN partial stats: per-(b,h)-block partial sum/sumsq -> private slot
// pstat2[(oc*2+st)*512 + b*64+h]; k8 reduces the 512 partials per channel.
__global__ void __launch_bounds__(256) k6_mfma(const u16* __restrict__ x2b, const u16* __restrict__ wb,
                                               float* __restrict__ y, float* __restrict__ pstat2) {
  __shared__ u16 Xl[3 * 66 * 72];
  __shared__ float pp[4][64][2];
  const int t = threadIdx.x, b = blockIdx.y, h = blockIdx.x;
  for (int idx = t; idx < 3 * 66 * 8; idx += 256) {
    int r = idx / 528;
    int rem = idx - r * 528;
    int c = rem >> 3, icq = rem & 7;
    int gy = h - 1 + r, gx = c - 1;
    u32x4 v = {0u, 0u, 0u, 0u};
    if (gy >= 0 && gy < 64 && gx >= 0 && gx < 64)
      v = *(const u32x4*)&x2b[(((size_t)(b << 6 | gy) << 6) + gx) * 64 + icq * 8];
    *(u32x4*)&Xl[(r * 66 + c) * 72 + icq * 8] = v;
  }
  __syncthreads();
  const int w = t >> 6, lane = t & 63, quad = lane >> 4, l16 = lane & 15;
  const int mBase = (w & 1) * 64;
  const int og = (w & 1) * 4;
  const int nBase = (w >> 1) * 32;
  f32x4 acc[4][2];
#pragma unroll
  for (int ot = 0; ot < 4; ++ot)
#pragma unroll
    for (int nt = 0; nt < 2; ++nt) acc[ot][nt] = (f32x4){0.f, 0.f, 0.f, 0.f};
#pragma unroll 3
  for (int tap = 0; tap < 9; ++tap) {
    const int dy = tap / 3, dx = tap - dy * 3;
    bf16x8 af[4][2];
#pragma unroll
    for (int ot = 0; ot < 4; ++ot)
#pragma unroll
      for (int kc = 0; kc < 2; ++kc)
        af[ot][kc] = *(const bf16x8*)&wb[((((tap * 8 + og + ot) * 2 + kc) << 6) + lane) << 3];
#pragma unroll
    for (int nt = 0; nt < 2; ++nt) {
      const int prow = dy * 66 + nBase + nt * 16 + l16 + dx;
#pragma unroll
      for (int kc = 0; kc < 2; ++kc) {
        bf16x8 bv = *(const bf16x8*)&Xl[prow * 72 + kc * 32 + quad * 8];
#pragma unroll
        for (int ot = 0; ot < 4; ++ot)
          acc[ot][nt] = __builtin_amdgcn_mfma_f32_16x16x32_bf16(af[ot][kc], bv, acc[ot][nt], 0, 0, 0);
      }
    }
  }
#pragma unroll
  for (int ot = 0; ot < 4; ++ot)
#pragma unroll
    for (int nt = 0; nt < 2; ++nt)
#pragma unroll
      for (int r = 0; r < 4; ++r) {
        int oc = mBase + ot * 16 + quad * 4 + r;
        int pix = nBase + nt * 16 + l16;
        y[((b * 128 + oc) << 12) + (h << 6) + pix] = acc[ot][nt][r];
      }
  // ---- fused BN partial stats
  float bs[4][4], bss[4][4];
#pragma unroll
  for (int ot = 0; ot < 4; ++ot)
#pragma unroll
    for (int r = 0; r < 4; ++r) {
      float v0 = acc[ot][0][r], v1 = acc[ot][1][r];
      bs[ot][r] = v0 + v1;
      bss[ot][r] = v0 * v0 + v1 * v1;
    }
#pragma unroll
  for (int off = 1; off < 16; off <<= 1) {
#pragma unroll
    for (int ot = 0; ot < 4; ++ot)
#pragma unroll
      for (int r = 0; r < 4; ++r) {
        bs[ot][r] += __shfl_xor(bs[ot][r], off);
        bss[ot][r] += __shfl_xor(bss[ot][r], off);
      }
  }
  if (l16 == 0) {
#pragma unroll
    for (int ot = 0; ot < 4; ++ot)
#pragma unroll
      for (int r = 0; r < 4; ++r) {
        int ocl = ot * 16 + quad * 4 + r;
        pp[w][ocl][0] = bs[ot][r];
        pp[w][ocl][1] = bss[ot][r];
      }
  }
  __syncthreads();
  {
    int oc = t >> 1, st = t & 1;
    float v = (oc < 64) ? (pp[0][oc][st] + pp[2][oc][st])
                        : (pp[1][oc - 64][st] + pp[3][oc - 64][st]);
    pstat2[(oc * 2 + st) * 512 + (b << 6) + h] = v;
  }
}

// ---------------- Kernel 8: BN finalize (from k6's 512 per-block partials) + ReLU + maxpool
__global__ void __launch_bounds__(256) k8_pool(const float* __restrict__ y, const float* __restrict__ pstat2,
                                               const float* __restrict__ gamma, const float* __restrict__ bbeta,
                                               float* __restrict__ out) {
  const int bc = blockIdx.x;
  const int ch = bc & 127;
  float s = 0.f, ss = 0.f;
  for (int i = threadIdx.x; i < 512; i += 256) {
    s += pstat2[ch * 1024 + i];
    ss += pstat2[ch * 1024 + 512 + i];
  }
#pragma unroll
  for (int off = 1; off < 64; off <<= 1) { s += __shfl_xor(s, off); ss += __shfl_xor(ss, off); }
  __shared__ float rs[4], rss[4];
  if ((threadIdx.x & 63) == 0) { rs[threadIdx.x >> 6] = s; rss[threadIdx.x >> 6] = ss; }
  __syncthreads();
  const float S = rs[0] + rs[1] + rs[2] + rs[3];
  const float SS = rss[0] + rss[1] + rss[2] + rss[3];
  const float mean = S * (1.f / 32768.f);
  const float var = SS * (1.f / 32768.f) - mean * mean;
  const float sc = gamma[ch] * rsqrtf(var + 1e-5f);
  const float sh = bbeta[ch] - mean * sc;
  const float* p = y + (bc << 12);
  float* op = out + bc * (33 * 32);
  for (int i = threadIdx.x; i < 33 * 32; i += 256) {
    int oh = i >> 5, ow = i & 31;
    int r0 = 2 * oh - 1, r1 = 2 * oh;
    float m = 0.f;
    if (r0 >= 0) {
      m = fmaxf(m, p[r0 * 64 + 2 * ow] * sc + sh);
      m = fmaxf(m, p[r0 * 64 + 2 * ow + 1] * sc + sh);
    }
    if (r1 <= 63) {
      m = fmaxf(m, p[r1 * 64 + 2 * ow] * sc + sh);
      m = fmaxf(m, p[r1 * 64 + 2 * ow + 1] * sc + sh);
    }
    op[i] = m;
  }
}

extern "C" void kernel_launch(void* const* d_in, const int* in_sizes, int n_in,
                              void* d_out, int out_size, void* d_ws, size_t ws_size,
                              hipStream_t stream) {
  const float* x      = (const float*)d_in[0];
  const float* wB     = (const float*)d_in[1];
  const float* bB     = (const float*)d_in[2];
  const float* wC     = (const float*)d_in[3];
  const float* bC     = (const float*)d_in[4];
  const float* wD     = (const float*)d_in[5];
  const float* bD     = (const float*)d_in[6];
  const float* alpha  = (const float*)d_in[7];
  const float* beta   = (const float*)d_in[8];
  const float* cw     = (const float*)d_in[9];
  const float* gamma  = (const float*)d_in[11];
  const float* bnbeta = (const float*)d_in[12];

  // Workspace overlays (35.3 MB):
  //  [0,4M):      featBb/featCb/fDb [k1..k2p]  then x2b [k5..k6]
  //  [5M,13M):    x1 [k3..k5]
  //  [13M,29.8M): numPart [k2p..k3]  then y [k6..k8]
  //  [29.0M+..]:  denPart, attPart (reused as pstat2 after k4), attP, wb
  char* ws = (char*)d_ws;
  u16*   featBb  = (u16*)  (ws + 0);          // 512 KB
  u16*   featCb  = (u16*)  (ws + 524288);     // 512 KB
  u16*   fDb     = (u16*)  (ws + 1048576);    // 4 MB
  u16*   x2b     = (u16*)  (ws + 0);          // 4 MB (bf16 NHWC) — over feat*
  float* x1      = (float*)(ws + 5242880);    // 8 MB
  u16*   numPart = (u16*)  (ws + 13631488);   // 16 MB
  float* y       = (float*)(ws + 13631488);   // 16 MB — over numPart
  float* denPart = (float*)(ws + 30408704);   // 512 KB
  float* attPart = (float*)(ws + 30932992);   // 4 MB
  float* pstat2  = (float*)(ws + 30932992);   // 512 KB — over attPart (dead after k4)
  float* attP    = (float*)(ws + 35127296);   // 128 KB
  u16*   wb      = (u16*)  (ws + 35258368);   // 144 KB
  float* outp    = (float*)d_out;

  k1_conv1x1<<<dim3(16, 8, 4), 256, 0, stream>>>(x, wB, bB, wC, bC, wD, bD, featBb, featCb, fDb, cw, wb);
  k2_pam_part<<<dim3(32, 8, 4), 256, 0, stream>>>(featBb, featCb, fDb, numPart, denPart);
  k3_gram<<<dim3(32, 8, 2), 256, 0, stream>>>(numPart, denPart, x, alpha, x1, attPart);
  k4_softmax<<<dim3(64, 8), 64, 0, stream>>>(attPart, attP);
  k5_apply<<<dim3(128, 8), 256, 0, stream>>>(attP, x1, beta, x2b);
  k6_mfma<<<dim3(64, 8), 256, 0, stream>>>(x2b, wb, y, pstat2);
  k8_pool<<<dim3(1024), 256, 0, stream>>>(y, pstat2, gamma, bnbeta, outp);
}